// Round 3
// baseline (102.569 us; speedup 1.0000x reference)
//
#include <hip/hip_runtime.h>
#include <hip/hip_bf16.h>
#include <math.h>

// GAT layer, V=8192, E=262144, D=128.
// out[i] = (S + sum_{distinct (i,j)} (exp(a_ij)-1)*hw[j]) / (V + sum (exp(a_ij)-1))
// a_ij = leakyrelu(s1[i]+s2[j], 0.2); s1/s2 = hw @ att halves; S = colsum(hw).
//
// R15 -> R16:
//  (1) k_hw: LDS-duplication fix. Old: c4=(t&31)*4 meant both half-waves read
//      the SAME Wt addresses -> each ds_read_b128 delivered only 512B distinct
//      (43 B/cyc vs 85 B/cyc pipe ceiling); k_hw was LDS-bound at ~5us.
//      New: 2 cols/lane (c2=(t&63)*2), 4 rows/thread, Wt reads are full-wave
//      distinct ds_read_b64 -> LDS cycles halve. hw accumulation order per
//      (row,col) unchanged -> hwb bit-identical.
//  (2) k_row: paired-entry gather. Even-slot entries -> lanes 0-31, odd ->
//      lanes 32-63; each lane owns 4 cols via one 8B load -> VMEM instrs
//      halved, one shfl_xor(32) fold at the end. deg padded to x8 (dead
//      slots carry w=0) -> both scalar tails deleted.
// k_scatter / S-reduce unchanged from verified R15.

#define V 8192
#define E 262144
#define D 128
#define NEG_SLOPE 0.2f
#define CAP 96     // bucket capacity/row; max expected degree ~55 (11-sigma safe)
#define CSTRIDE 16 // cnt padded: one counter per 64B cache line
#define HWB 512    // k_hw grid

__device__ __forceinline__ unsigned short f2bf(float f) {   // RNE fp32->bf16
    unsigned u = __float_as_uint(f);
    return (unsigned short)((u + 0x7fffu + ((u >> 16) & 1u)) >> 16);
}
__device__ __forceinline__ float bf2f_low(int p) {          // low 16 bits -> float
    return __uint_as_float(((unsigned)p) << 16);
}

// ---------------- K1: hw(bf16) = h @ W^T, fused s1/s2 + colsum partials ------
// 512 blocks x 256 thr, 16 rows/block, 4 rows/wave, 2 cols/lane.
__global__ __launch_bounds__(256) void k_hw(const float* __restrict__ h,
                                            const float* __restrict__ W,
                                            const float* __restrict__ att,
                                            unsigned short* __restrict__ hwb,
                                            float* __restrict__ s1,
                                            float* __restrict__ s2,
                                            float* __restrict__ Pb,
                                            int* __restrict__ cnt) {
    __shared__ float Wt[D * 130];      // W transposed, pad 130 (keeps 8B align)
    __shared__ float atts[2 * D];
    __shared__ float scr[4 * D];       // colsum scratch (1 partial per wave)
    int t = threadIdx.x, b = blockIdx.x;
    int g = b * 256 + t;               // 512*256 = 131072 = V*CSTRIDE exactly
    cnt[g] = 0;
    atts[t] = att[t];
    // scalar-coalesced staging: lane-fast k, write stride 130 floats
    for (int f = t; f < D * D; f += 256) {
        int o = f >> 7, k = f & 127;
        Wt[k * 130 + o] = W[f];        // W[o][k] -> Wt[k][o]
    }
    __syncthreads();

    int l = t & 63;
    int ww = t >> 6;                   // wave id 0..3
    int c2 = l * 2;                    // 2-col group, full wave spans 128 cols
    int r0 = b * 16 + ww * 4;          // wave's 4 rows
    float2 a0 = make_float2(0.f, 0.f), a1 = a0, a2 = a0, a3 = a0;
    const float* h0p = &h[(r0 + 0) * D];
    const float* h1p = &h[(r0 + 1) * D];
    const float* h2p = &h[(r0 + 2) * D];
    const float* h3p = &h[(r0 + 3) * D];
    #pragma unroll 4
    for (int kq = 0; kq < D; kq += 4) {
        float2 w0 = *(const float2*)&Wt[(kq + 0) * 130 + c2];  // ds_read_b64,
        float2 w1 = *(const float2*)&Wt[(kq + 1) * 130 + c2];  // 64 lanes all
        float2 w2 = *(const float2*)&Wt[(kq + 2) * 130 + c2];  // distinct data
        float2 w3 = *(const float2*)&Wt[(kq + 3) * 130 + c2];
        float4 hv;
        hv = *(const float4*)&h0p[kq];   // wave-broadcast 16B
        a0.x += hv.x*w0.x; a0.y += hv.x*w0.y;
        a0.x += hv.y*w1.x; a0.y += hv.y*w1.y;
        a0.x += hv.z*w2.x; a0.y += hv.z*w2.y;
        a0.x += hv.w*w3.x; a0.y += hv.w*w3.y;
        hv = *(const float4*)&h1p[kq];
        a1.x += hv.x*w0.x; a1.y += hv.x*w0.y;
        a1.x += hv.y*w1.x; a1.y += hv.y*w1.y;
        a1.x += hv.z*w2.x; a1.y += hv.z*w2.y;
        a1.x += hv.w*w3.x; a1.y += hv.w*w3.y;
        hv = *(const float4*)&h2p[kq];
        a2.x += hv.x*w0.x; a2.y += hv.x*w0.y;
        a2.x += hv.y*w1.x; a2.y += hv.y*w1.y;
        a2.x += hv.z*w2.x; a2.y += hv.z*w2.y;
        a2.x += hv.w*w3.x; a2.y += hv.w*w3.y;
        hv = *(const float4*)&h3p[kq];
        a3.x += hv.x*w0.x; a3.y += hv.x*w0.y;
        a3.x += hv.y*w1.x; a3.y += hv.y*w1.y;
        a3.x += hv.z*w2.x; a3.y += hv.z*w2.y;
        a3.x += hv.w*w3.x; a3.y += hv.w*w3.y;
    }
    *(ushort2*)&hwb[(r0 + 0) * D + c2] = make_ushort2(f2bf(a0.x), f2bf(a0.y));
    *(ushort2*)&hwb[(r0 + 1) * D + c2] = make_ushort2(f2bf(a1.x), f2bf(a1.y));
    *(ushort2*)&hwb[(r0 + 2) * D + c2] = make_ushort2(f2bf(a2.x), f2bf(a2.y));
    *(ushort2*)&hwb[(r0 + 3) * D + c2] = make_ushort2(f2bf(a3.x), f2bf(a3.y));

    // fused s1/s2 (fp32), 4 rows, 2-col partial + 64-lane butterfly reduce
    float q1_0 = a0.x * atts[c2] + a0.y * atts[c2 + 1];
    float q2_0 = a0.x * atts[D + c2] + a0.y * atts[D + c2 + 1];
    float q1_1 = a1.x * atts[c2] + a1.y * atts[c2 + 1];
    float q2_1 = a1.x * atts[D + c2] + a1.y * atts[D + c2 + 1];
    float q1_2 = a2.x * atts[c2] + a2.y * atts[c2 + 1];
    float q2_2 = a2.x * atts[D + c2] + a2.y * atts[D + c2 + 1];
    float q1_3 = a3.x * atts[c2] + a3.y * atts[c2 + 1];
    float q2_3 = a3.x * atts[D + c2] + a3.y * atts[D + c2 + 1];
    #pragma unroll
    for (int m = 32; m; m >>= 1) {
        q1_0 += __shfl_xor(q1_0, m);
        q2_0 += __shfl_xor(q2_0, m);
        q1_1 += __shfl_xor(q1_1, m);
        q2_1 += __shfl_xor(q2_1, m);
        q1_2 += __shfl_xor(q1_2, m);
        q2_2 += __shfl_xor(q2_2, m);
        q1_3 += __shfl_xor(q1_3, m);
        q2_3 += __shfl_xor(q2_3, m);
    }
    if (l == 0) {
        s1[r0 + 0] = q1_0;  s2[r0 + 0] = q2_0;
        s1[r0 + 1] = q1_1;  s2[r0 + 1] = q2_1;
        s1[r0 + 2] = q1_2;  s2[r0 + 2] = q2_2;
        s1[r0 + 3] = q1_3;  s2[r0 + 3] = q2_3;
    }

    // colsum partial: wave's 4-row sums -> LDS (b64, conflict-free)
    *(float2*)&scr[ww * D + c2] = make_float2(a0.x + a1.x + a2.x + a3.x,
                                              a0.y + a1.y + a2.y + a3.y);
    __syncthreads();
    if (t < D) {
        float s = scr[t] + scr[D + t] + scr[2 * D + t] + scr[3 * D + t];
        Pb[b * D + t] = s;
    }
}

// ---------------- K2: scatter (b<1024, 1 edge/thr) | S-reduce (b>=1024) -----
__global__ __launch_bounds__(256) void k_scatter(const int* __restrict__ ei,
                                                 const float* __restrict__ s1,
                                                 const float* __restrict__ s2,
                                                 int* __restrict__ cnt,
                                                 int* __restrict__ bucket,
                                                 const float* __restrict__ Pb,
                                                 float* __restrict__ S) {
    int b = blockIdx.x, t = threadIdx.x;
    if (b < 1024) {
        int g = b * 256 + t;               // one edge/thread: single atomic
        int src = ei[g];
        int dst = ei[E + g];
        float a = s1[src] + s2[dst];
        a = a > 0.f ? a : NEG_SLOPE * a;
        float w = expf(a) - 1.f;
        int pos = atomicAdd(&cnt[src * CSTRIDE], 1);   // private 64B line per row
        if (pos < CAP)
            bucket[src * CAP + pos] = (dst << 16) | (int)f2bf(w);  // 4B packed
    } else {
        // 4 reduce blocks, 32 cols each; 8-way row split, coalesced 128B reads
        __shared__ float red[256];
        int bb = b - 1024;                 // 0..3
        int c = bb * 32 + (t & 31);        // column
        int rg = t >> 5;                   // 0..7
        float s = 0.f;
        #pragma unroll 4
        for (int r = rg; r < HWB; r += 8)
            s += Pb[r * D + c];
        red[t] = s;
        __syncthreads();
        if (t < 32) {
            float v = red[t] + red[t + 32] + red[t + 64] + red[t + 96]
                    + red[t + 128] + red[t + 160] + red[t + 192] + red[t + 224];
            S[bb * 32 + t] = v;
        }
    }
}

// ---------------- K3: per-row gather, paired 8B loads, bitmap-prepass dedup --
// 2048 blocks x 256 thr, 1 row/wave. Even slots -> lanes 0-31, odd -> 32-63;
// each lane owns 4 cols (8B hwb load); shfl_xor(32) fold merges halves.
__global__ __launch_bounds__(256) void k_row(const int* __restrict__ bucket,
                                             const int* __restrict__ cnt,
                                             const unsigned short* __restrict__ hwb,
                                             const float* __restrict__ S,
                                             float* __restrict__ out) {
    __shared__ int lb[4][CAP];             // 1.5KB, 16B-aligned per wave
    __shared__ unsigned bm[4][256];        // 8192-bit dedup bitmap per wave (4KB)
    int t = threadIdx.x;
    int wv = t >> 6, lane = t & 63;
    int row = blockIdx.x * 4 + wv;
    int deg = cnt[row * CSTRIDE];
    if (deg > CAP) deg = CAP;
    // zero wave-private bitmap: 64 lanes x 16B, conflict-free
    *(uint4*)&bm[wv][lane * 4] = make_uint4(0u, 0u, 0u, 0u);
    const int* bk = bucket + row * CAP;
    int e0 = bk[lane];
    int e1 = (lane < CAP - 64) ? bk[64 + lane] : 0;
    int p0 = (lane < deg)      ? e0 : 0;   // dead slots: d=0, w=0
    int p1 = (64 + lane < deg) ? e1 : 0;
    // dedup pre-pass: exactly one claimant per dst survives (dup w bit-identical)
    if (lane < deg) {
        unsigned d = (unsigned)p0 >> 16;
        unsigned m = 1u << (d & 31);
        if (atomicOr(&bm[wv][d >> 5], m) & m) p0 &= ~0xFFFF;   // loser: w=0
    }
    if (64 + lane < deg) {
        unsigned d = (unsigned)p1 >> 16;
        unsigned m = 1u << (d & 31);
        if (atomicOr(&bm[wv][d >> 5], m) & m) p1 &= ~0xFFFF;
    }
    lb[wv][lane] = p0;
    if (lane < CAP - 64) lb[wv][64 + lane] = p1;
    const int* myb = lb[wv];
    int li = lane & 31, half = lane >> 5;
    int col4 = li * 4;                     // this lane's 4 columns
    float ax = 0.f, ay = 0.f, az = 0.f, aw = 0.f, dex = 0.f;
    int nr = (deg + 7) & ~7;               // pad to x8; dead slots contribute 0

    #define PROC(EV, OD) { \
        int ps_ = half ? (OD) : (EV); \
        int ds_ = ps_ >> 16; \
        float ws_ = bf2f_low(ps_); \
        unsigned long long hv_ = *(const unsigned long long*)&hwb[ds_ * D + col4]; \
        unsigned lo_ = (unsigned)hv_, hi_ = (unsigned)(hv_ >> 32); \
        ax += ws_ * __uint_as_float(lo_ << 16); \
        ay += ws_ * __uint_as_float(lo_ & 0xFFFF0000u); \
        az += ws_ * __uint_as_float(hi_ << 16); \
        aw += ws_ * __uint_as_float(hi_ & 0xFFFF0000u); \
        dex += ws_; }

    for (int j = 0; j < nr; j += 8) {
        int4 pa = *(const int4*)&myb[j];        // 2x ds_read_b128 broadcast
        int4 pb = *(const int4*)&myb[j + 4];
        PROC(pa.x, pa.y)
        PROC(pa.z, pa.w)
        PROC(pb.x, pb.y)
        PROC(pb.z, pb.w)
    }
    #undef PROC

    // fold halves: lanes l and l+32 then both hold full sums for cols col4..+3
    ax += __shfl_xor(ax, 32);
    ay += __shfl_xor(ay, 32);
    az += __shfl_xor(az, 32);
    aw += __shfl_xor(aw, 32);
    dex += __shfl_xor(dex, 32);
    float inv = 1.f / ((float)V + dex);
    int c = col4 + half * 2;               // half0 writes cols 0-1, half1 2-3
    float2 sv = *(const float2*)&S[c];
    float2 o;
    o.x = ((half ? az : ax) + sv.x) * inv;
    o.y = ((half ? aw : ay) + sv.y) * inv;
    *(float2*)&out[row * D + c] = o;
}

extern "C" void kernel_launch(void* const* d_in, const int* in_sizes, int n_in,
                              void* d_out, int out_size, void* d_ws, size_t ws_size,
                              hipStream_t stream) {
    const float* h   = (const float*)d_in[0];
    const int*   ei  = (const int*)d_in[1];
    const float* W   = (const float*)d_in[2];
    const float* att = (const float*)d_in[3];
    float* out = (float*)d_out;

    char* ws = (char*)d_ws;
    // workspace layout (bytes):
    //   hwb    @ 0          2,097,152   (bf16 hw)
    //   s1     @ 2,097,152     32,768
    //   s2     @ 2,129,920     32,768
    //   S      @ 2,162,688        512
    //   cnt    @ 2,163,200    524,288   (V counters padded to 64B lines)
    //   bucket @ 2,687,488  3,145,728   (8192 * 96 * 4B packed)
    //   Pb     @ 5,833,216    262,144   (512 blocks * 128 colsum partials)
    unsigned short* hwb = (unsigned short*)(ws);
    float* s1  = (float*)(ws + 2097152);
    float* s2  = (float*)(ws + 2129920);
    float* S   = (float*)(ws + 2162688);
    int*   cnt = (int*)(ws + 2163200);
    int*   bucket = (int*)(ws + 2687488);
    float* Pb  = (float*)(ws + 5833216);

    k_hw     <<<HWB,  256, 0, stream>>>(h, W, att, hwb, s1, s2, Pb, cnt);
    k_scatter<<<1028, 256, 0, stream>>>(ei, s1, s2, cnt, bucket, Pb, S);
    k_row    <<<2048, 256, 0, stream>>>(bucket, cnt, hwb, S, out);
}

// Round 4
// 98.295 us; speedup vs baseline: 1.0435x; 1.0435x over previous
//
#include <hip/hip_runtime.h>
#include <hip/hip_bf16.h>
#include <math.h>

// GAT layer, V=8192, E=262144, D=128.
// out[i] = (S + sum_{distinct (i,j)} (exp(a_ij)-1)*hw[j]) / (V + sum (exp(a_ij)-1))
// a_ij = leakyrelu(s1[i]+s2[j], 0.2); s1/s2 = hw @ att halves; S = colsum(hw).
//
// R16 -> R17: REVERT to verified R15 (97.07us). R16's k_hw theory was wrong
// (half-wave duplicate addresses are same-address broadcasts = free; distinct
// bytes/cyc identical), and the k_row paired-load restructure regressed 5.5us
// (select-before-address dependency + strided epilogue stores). Only change
// kept on top of the R15 base: k_scatter expf -> __expf (v_exp_f32 path,
// ~1e-6 rel err, 3 orders below the 2.44e-4 bf16 floor).
// Accounting: ~84us of the window is two invariant 256MB harness poison
// fills; our 3 kernels total ~13us vs ~11us model floor.

#define V 8192
#define E 262144
#define D 128
#define NEG_SLOPE 0.2f
#define CAP 96     // bucket capacity/row; max expected degree ~55 (11-sigma safe)
#define CSTRIDE 16 // cnt padded: one counter per 64B cache line
#define HWB 512    // k_hw grid

#define FMA4(acc, hv, wv) { acc.x += (hv)*(wv).x; acc.y += (hv)*(wv).y; \
                            acc.z += (hv)*(wv).z; acc.w += (hv)*(wv).w; }

__device__ __forceinline__ unsigned short f2bf(float f) {   // RNE fp32->bf16
    unsigned u = __float_as_uint(f);
    return (unsigned short)((u + 0x7fffu + ((u >> 16) & 1u)) >> 16);
}
__device__ __forceinline__ float bf2f_low(int p) {          // low 16 bits -> float
    return __uint_as_float(((unsigned)p) << 16);
}

// ---------------- K1: hw(bf16) = h @ W^T, fused s1/s2 + colsum partials ------
// 512 blocks x 256 thr, 16 rows/block, 2 rows/thread, 2 waves/SIMD.
__global__ __launch_bounds__(256) void k_hw(const float* __restrict__ h,
                                            const float* __restrict__ W,
                                            const float* __restrict__ att,
                                            unsigned short* __restrict__ hwb,
                                            float* __restrict__ s1,
                                            float* __restrict__ s2,
                                            float* __restrict__ Pb,
                                            int* __restrict__ cnt) {
    __shared__ float Wt[D * 132];      // W transposed, pad 132
    __shared__ float atts[2 * D];
    __shared__ float scr[8 * D];       // colsum scratch
    int t = threadIdx.x, b = blockIdx.x;
    int g = b * 256 + t;               // 512*256 = 131072 = V*CSTRIDE exactly
    cnt[g] = 0;
    atts[t] = att[t];
    // scalar-coalesced staging: lane-fast k, write stride 132 floats (8-way)
    for (int f = t; f < D * D; f += 256) {
        int o = f >> 7, k = f & 127;
        Wt[k * 132 + o] = W[f];        // W[o][k] -> Wt[k][o]
    }
    __syncthreads();

    int c4 = (t & 31) * 4;   // 4-col group
    int rq = t >> 5;         // 0..7; rows rq, rq+8
    int r0 = b * 16;
    float4 a0 = make_float4(0.f,0.f,0.f,0.f), a1 = a0;
    const float* h0p = &h[(r0 + rq    ) * D];
    const float* h1p = &h[(r0 + rq + 8) * D];
    #pragma unroll 4
    for (int kq = 0; kq < D; kq += 4) {
        float4 w0 = *(const float4*)&Wt[(kq + 0) * 132 + c4];
        float4 w1 = *(const float4*)&Wt[(kq + 1) * 132 + c4];
        float4 w2 = *(const float4*)&Wt[(kq + 2) * 132 + c4];
        float4 w3 = *(const float4*)&Wt[(kq + 3) * 132 + c4];
        float4 hv;
        hv = *(const float4*)&h0p[kq];   // wave-broadcast 16B
        FMA4(a0, hv.x, w0); FMA4(a0, hv.y, w1); FMA4(a0, hv.z, w2); FMA4(a0, hv.w, w3);
        hv = *(const float4*)&h1p[kq];
        FMA4(a1, hv.x, w0); FMA4(a1, hv.y, w1); FMA4(a1, hv.z, w2); FMA4(a1, hv.w, w3);
    }
    *(ushort4*)&hwb[(r0 + rq    ) * D + c4] = make_ushort4(f2bf(a0.x), f2bf(a0.y), f2bf(a0.z), f2bf(a0.w));
    *(ushort4*)&hwb[(r0 + rq + 8) * D + c4] = make_ushort4(f2bf(a1.x), f2bf(a1.y), f2bf(a1.z), f2bf(a1.w));

    // fused s1/s2 (fp32, 32-lane group reduce), 2 rows
    float q1a = a0.x * atts[c4] + a0.y * atts[c4 + 1] + a0.z * atts[c4 + 2] + a0.w * atts[c4 + 3];
    float q2a = a0.x * atts[D + c4] + a0.y * atts[D + c4 + 1] + a0.z * atts[D + c4 + 2] + a0.w * atts[D + c4 + 3];
    float q1b = a1.x * atts[c4] + a1.y * atts[c4 + 1] + a1.z * atts[c4 + 2] + a1.w * atts[c4 + 3];
    float q2b = a1.x * atts[D + c4] + a1.y * atts[D + c4 + 1] + a1.z * atts[D + c4 + 2] + a1.w * atts[D + c4 + 3];
    #pragma unroll
    for (int m = 16; m; m >>= 1) {
        q1a += __shfl_xor(q1a, m);
        q2a += __shfl_xor(q2a, m);
        q1b += __shfl_xor(q1b, m);
        q2b += __shfl_xor(q2b, m);
    }
    if ((t & 31) == 0) {
        s1[r0 + rq    ] = q1a;
        s2[r0 + rq    ] = q2a;
        s1[r0 + rq + 8] = q1b;
        s2[r0 + rq + 8] = q2b;
    }

    // colsum partial: 2-row sums -> LDS (b128, conflict-free) -> Pb[b][col]
    *(float4*)&scr[rq * D + c4] = make_float4(a0.x + a1.x, a0.y + a1.y,
                                              a0.z + a1.z, a0.w + a1.w);
    __syncthreads();
    if (t < D) {
        float s = 0.f;
        #pragma unroll
        for (int r = 0; r < 8; ++r) s += scr[r * D + t];
        Pb[b * D + t] = s;
    }
}

// ---------------- K2: scatter (b<1024, 1 edge/thr) | S-reduce (b>=1024) -----
__global__ __launch_bounds__(256) void k_scatter(const int* __restrict__ ei,
                                                 const float* __restrict__ s1,
                                                 const float* __restrict__ s2,
                                                 int* __restrict__ cnt,
                                                 int* __restrict__ bucket,
                                                 const float* __restrict__ Pb,
                                                 float* __restrict__ S) {
    int b = blockIdx.x, t = threadIdx.x;
    if (b < 1024) {
        int g = b * 256 + t;               // one edge/thread: single atomic
        int src = ei[g];
        int dst = ei[E + g];
        float a = s1[src] + s2[dst];
        a = a > 0.f ? a : NEG_SLOPE * a;
        float w = __expf(a) - 1.f;         // v_exp_f32 path; err ~1e-6 rel
        int pos = atomicAdd(&cnt[src * CSTRIDE], 1);   // private 64B line per row
        if (pos < CAP)
            bucket[src * CAP + pos] = (dst << 16) | (int)f2bf(w);  // 4B packed
    } else {
        // 4 reduce blocks, 32 cols each; 8-way row split, coalesced 128B reads
        __shared__ float red[256];
        int bb = b - 1024;                 // 0..3
        int c = bb * 32 + (t & 31);        // column
        int rg = t >> 5;                   // 0..7
        float s = 0.f;
        #pragma unroll 4
        for (int r = rg; r < HWB; r += 8)
            s += Pb[r * D + c];
        red[t] = s;
        __syncthreads();
        if (t < 32) {
            float v = red[t] + red[t + 32] + red[t + 64] + red[t + 96]
                    + red[t + 128] + red[t + 160] + red[t + 192] + red[t + 224];
            S[bb * 32 + t] = v;
        }
    }
}

// ---------------- K3: per-row gather, 8 entries/iter, bitmap-prepass dedup ---
// 2048 blocks x 256 thr, 1 row/wave. LDS-staged bucket, b128 broadcasts.
// Dedup done ONCE up front: wave-private 8192-bit LDS bitmap, atomicOr claim,
// losers zero their packed w in LDS. Main loop is ballot-free.
__global__ __launch_bounds__(256) void k_row(const int* __restrict__ bucket,
                                             const int* __restrict__ cnt,
                                             const unsigned short* __restrict__ hwb,
                                             const float* __restrict__ S,
                                             float* __restrict__ out) {
    __shared__ int lb[4][CAP];             // 1.5KB, 16B-aligned per wave
    __shared__ unsigned bm[4][256];        // 8192-bit dedup bitmap per wave (4KB)
    int t = threadIdx.x;
    int wv = t >> 6, lane = t & 63;
    int row = blockIdx.x * 4 + wv;
    int deg = cnt[row * CSTRIDE];
    if (deg > CAP) deg = CAP;
    // zero wave-private bitmap: 64 lanes x 16B, conflict-free
    *(uint4*)&bm[wv][lane * 4] = make_uint4(0u, 0u, 0u, 0u);
    const int* bk = bucket + row * CAP;
    int e0 = bk[lane];
    int e1 = (lane < CAP - 64) ? bk[64 + lane] : 0;
    int p0 = (lane < deg)      ? e0 : 0;   // dead slots: d=0, w=0
    int p1 = (64 + lane < deg) ? e1 : 0;
    // dedup pre-pass: exactly one claimant per dst survives (dup w bit-identical)
    if (lane < deg) {
        unsigned d = (unsigned)p0 >> 16;
        unsigned m = 1u << (d & 31);
        if (atomicOr(&bm[wv][d >> 5], m) & m) p0 &= ~0xFFFF;   // loser: w=0
    }
    if (64 + lane < deg) {
        unsigned d = (unsigned)p1 >> 16;
        unsigned m = 1u << (d & 31);
        if (atomicOr(&bm[wv][d >> 5], m) & m) p1 &= ~0xFFFF;
    }
    lb[wv][lane] = p0;
    if (lane < CAP - 64) lb[wv][64 + lane] = p1;
    int n0 = deg < 64 ? deg : 64;
    float accx = 0.f, accy = 0.f, dex = 0.f;
    const int* myb = lb[wv];
    int col2 = lane * 2;
    int j = 0;
    for (; j + 8 <= n0; j += 8) {
        int4 pa = *(const int4*)&myb[j];        // 2x ds_read_b128 broadcast
        int4 pb = *(const int4*)&myb[j + 4];
        int da0 = pa.x >> 16, da1 = pa.y >> 16, da2 = pa.z >> 16, da3 = pa.w >> 16;
        int db0 = pb.x >> 16, db1 = pb.y >> 16, db2 = pb.z >> 16, db3 = pb.w >> 16;
        unsigned ha0 = *(const unsigned*)&hwb[da0 * D + col2];   // 8 in flight
        unsigned ha1 = *(const unsigned*)&hwb[da1 * D + col2];
        unsigned ha2 = *(const unsigned*)&hwb[da2 * D + col2];
        unsigned ha3 = *(const unsigned*)&hwb[da3 * D + col2];
        unsigned hb0 = *(const unsigned*)&hwb[db0 * D + col2];
        unsigned hb1 = *(const unsigned*)&hwb[db1 * D + col2];
        unsigned hb2 = *(const unsigned*)&hwb[db2 * D + col2];
        unsigned hb3 = *(const unsigned*)&hwb[db3 * D + col2];
        float wa0 = bf2f_low(pa.x);
        float wa1 = bf2f_low(pa.y);
        float wa2 = bf2f_low(pa.z);
        float wa3 = bf2f_low(pa.w);
        float wb0 = bf2f_low(pb.x);
        float wb1 = bf2f_low(pb.y);
        float wb2 = bf2f_low(pb.z);
        float wb3 = bf2f_low(pb.w);
        accx += wa0 * __uint_as_float(ha0 << 16);
        accy += wa0 * __uint_as_float(ha0 & 0xFFFF0000u);
        accx += wa1 * __uint_as_float(ha1 << 16);
        accy += wa1 * __uint_as_float(ha1 & 0xFFFF0000u);
        accx += wa2 * __uint_as_float(ha2 << 16);
        accy += wa2 * __uint_as_float(ha2 & 0xFFFF0000u);
        accx += wa3 * __uint_as_float(ha3 << 16);
        accy += wa3 * __uint_as_float(ha3 & 0xFFFF0000u);
        accx += wb0 * __uint_as_float(hb0 << 16);
        accy += wb0 * __uint_as_float(hb0 & 0xFFFF0000u);
        accx += wb1 * __uint_as_float(hb1 << 16);
        accy += wb1 * __uint_as_float(hb1 & 0xFFFF0000u);
        accx += wb2 * __uint_as_float(hb2 << 16);
        accy += wb2 * __uint_as_float(hb2 & 0xFFFF0000u);
        accx += wb3 * __uint_as_float(hb3 << 16);
        accy += wb3 * __uint_as_float(hb3 & 0xFFFF0000u);
        dex += wa0 + wa1 + wa2 + wa3 + wb0 + wb1 + wb2 + wb3;
    }
    for (; j < n0; ++j) {                   // tail (<8 entries)
        int pj = myb[j];
        int dj = pj >> 16;
        float wj = bf2f_low(pj);
        unsigned hv = *(const unsigned*)&hwb[dj * D + col2];
        accx += wj * __uint_as_float(hv << 16);
        accy += wj * __uint_as_float(hv & 0xFFFF0000u);
        dex += wj;
    }
    for (j = 64; j < deg; ++j) {            // slots 64..95 (rare: deg>64)
        int pj = myb[j];
        int dj = pj >> 16;
        float wj = bf2f_low(pj);
        unsigned hv = *(const unsigned*)&hwb[dj * D + col2];
        accx += wj * __uint_as_float(hv << 16);
        accy += wj * __uint_as_float(hv & 0xFFFF0000u);
        dex += wj;
    }
    float inv = 1.f / ((float)V + dex);
    float2 s = *(const float2*)&S[col2];
    float2 o;
    o.x = (s.x + accx) * inv;
    o.y = (s.y + accy) * inv;
    *(float2*)&out[row * D + col2] = o;
}

extern "C" void kernel_launch(void* const* d_in, const int* in_sizes, int n_in,
                              void* d_out, int out_size, void* d_ws, size_t ws_size,
                              hipStream_t stream) {
    const float* h   = (const float*)d_in[0];
    const int*   ei  = (const int*)d_in[1];
    const float* W   = (const float*)d_in[2];
    const float* att = (const float*)d_in[3];
    float* out = (float*)d_out;

    char* ws = (char*)d_ws;
    // workspace layout (bytes):
    //   hwb    @ 0          2,097,152   (bf16 hw)
    //   s1     @ 2,097,152     32,768
    //   s2     @ 2,129,920     32,768
    //   S      @ 2,162,688        512
    //   cnt    @ 2,163,200    524,288   (V counters padded to 64B lines)
    //   bucket @ 2,687,488  3,145,728   (8192 * 96 * 4B packed)
    //   Pb     @ 5,833,216    262,144   (512 blocks * 128 colsum partials)
    unsigned short* hwb = (unsigned short*)(ws);
    float* s1  = (float*)(ws + 2097152);
    float* s2  = (float*)(ws + 2129920);
    float* S   = (float*)(ws + 2162688);
    int*   cnt = (int*)(ws + 2163200);
    int*   bucket = (int*)(ws + 2687488);
    float* Pb  = (float*)(ws + 5833216);

    k_hw     <<<HWB,  256, 0, stream>>>(h, W, att, hwb, s1, s2, Pb, cnt);
    k_scatter<<<1028, 256, 0, stream>>>(ei, s1, s2, cnt, bucket, Pb, S);
    k_row    <<<2048, 256, 0, stream>>>(bucket, cnt, hwb, S, out);
}